// Round 3
// baseline (405.156 us; speedup 1.0000x reference)
//
#include <hip/hip_runtime.h>
#include <math.h>

#define MIN_NORM 1e-15f
#define BALL_EPS 4e-3f

__device__ __forceinline__ float wsum(float v) {
#pragma unroll
  for (int off = 32; off; off >>= 1) v += __shfl_xor(v, off, 64);
  return v;
}

__device__ __forceinline__ float artanh_clip(float z) {
  z = fminf(fmaxf(z, -1.0f + 1e-7f), 1.0f - 1e-7f);
  return 0.5f * (log1pf(z) - log1pf(-z));
}

// Phase 1: per-row  h = logmap0(mobius_add(mobius_matvec(W, x, c), hyp_bias, c), c)
// One wave per row (lane = output dim, OUT=64). W staged in LDS (256x64 f32 = 64KB).
__global__ __launch_bounds__(256) void hyp_linear_kernel(
    const float* __restrict__ x, const float* __restrict__ W,
    const float* __restrict__ bias, const float* __restrict__ cptr,
    float* __restrict__ h, int N) {
  __shared__ float sW[256 * 64];   // 64 KB
  __shared__ float sx[4][256];     // per-wave x row staging
  const int tid = threadIdx.x;
  const int lane = tid & 63;
  const int wid = tid >> 6;
  const float c = *cptr;
  const float sc = sqrtf(c);

  // cooperative W load: 16384 floats, float4 per thread per iter
  for (int i = tid * 4; i < 256 * 64; i += 1024)
    *(float4*)&sW[i] = *(const float4*)&W[i];

  // hyp_bias = proj(expmap0(bias, c), c) -- per lane o
  float b = bias[lane];
  float bnorm = fmaxf(sqrtf(wsum(b * b)), MIN_NORM);
  float tb = tanhf(sc * bnorm);
  float hb = tb * b / (sc * bnorm);
  float hbn = fmaxf(tb / sc, MIN_NORM);  // == ||hb||
  const float maxnorm = (1.0f - BALL_EPS) / sc;
  if (hbn > maxnorm) hb = hb / hbn * maxnorm;
  const float y2 = wsum(hb * hb);
  __syncthreads();

  const int nwaves = gridDim.x * 4;
  for (int r = blockIdx.x * 4 + wid; r < N; r += nwaves) {
    // stage x row (256 f32) into this wave's LDS buffer; compute ||x||^2
    float4 xv = *(const float4*)&x[(size_t)r * 256 + lane * 4];
    *(float4*)&sx[wid][lane * 4] = xv;
    float x2 = wsum(xv.x * xv.x + xv.y * xv.y + xv.z * xv.z + xv.w * xv.w);
    // cross-lane LDS visibility within the wave (no block barrier: waves run
    // independent rows; LDS ops are in-order per wave, just drain lgkm)
    asm volatile("s_waitcnt lgkmcnt(0)" ::: "memory");

    // mx[lane] = dot(x_row, W[:,lane])
    float acc = 0.0f;
#pragma unroll
    for (int i = 0; i < 256; i += 4) {
      float4 xq = *(const float4*)&sx[wid][i];  // wave-uniform broadcast
      acc = fmaf(xq.x, sW[(i + 0) * 64 + lane], acc);
      acc = fmaf(xq.y, sW[(i + 1) * 64 + lane], acc);
      acc = fmaf(xq.z, sW[(i + 2) * 64 + lane], acc);
      acc = fmaf(xq.w, sW[(i + 3) * 64 + lane], acc);
    }

    float mx = acc;
    int allzero = __all(mx == 0.0f);
    float mx_norm = fmaxf(sqrtf(wsum(mx * mx)), MIN_NORM);
    float x_norm = fmaxf(sqrtf(x2), MIN_NORM);
    float art = artanh_clip(sc * x_norm);
    float t = tanhf(mx_norm / x_norm * art);
    float res = t * mx / (mx_norm * sc);
    if (allzero) res = 0.0f;

    // mobius_add(res, hb, c)
    float x2m = wsum(res * res);
    float xy = wsum(res * hb);
    float k = 1.0f + 2.0f * c * xy;
    float num = (k + c * y2) * res + (1.0f - c * x2m) * hb;
    float den = k + c * c * x2m * y2;
    float ma = num / fmaxf(den, MIN_NORM);

    // logmap0
    float p_norm = fmaxf(sqrtf(wsum(ma * ma)), MIN_NORM);
    float art2 = artanh_clip(sc * p_norm);
    h[(size_t)r * 64 + lane] = art2 * ma / (sc * p_norm);
  }
}

// Phase 2: out[row[e]] += vals[e] * h[col[e]]   (wave per edge, lane = dim)
__global__ __launch_bounds__(256) void edge_kernel(
    const float* __restrict__ h, const float* __restrict__ vals,
    const int* __restrict__ row, const int* __restrict__ col,
    float* __restrict__ out, int E) {
  const int lane = threadIdx.x & 63;
  const int wid0 = (blockIdx.x * blockDim.x + threadIdx.x) >> 6;
  const int nw = (gridDim.x * blockDim.x) >> 6;
  for (int e = wid0; e < E; e += nw) {
    int eu = __builtin_amdgcn_readfirstlane(e);  // force scalar loads
    float v = vals[eu];
    int r = row[eu];
    int cl = col[eu];
    float hv = h[(size_t)cl * 64 + lane];
    atomicAdd(&out[(size_t)r * 64 + lane], v * hv);
  }
}

// Phase 3: out = proj(expmap0(out, c), c)  in place, wave per row
__global__ __launch_bounds__(256) void final_kernel(
    float* __restrict__ out, const float* __restrict__ cptr, int N) {
  const int lane = threadIdx.x & 63;
  const int wid0 = (blockIdx.x * blockDim.x + threadIdx.x) >> 6;
  const int nw = (gridDim.x * blockDim.x) >> 6;
  const float c = *cptr;
  const float sc = sqrtf(c);
  const float maxnorm = (1.0f - BALL_EPS) / sc;
  for (int r = wid0; r < N; r += nw) {
    float u = out[(size_t)r * 64 + lane];
    float un = fmaxf(sqrtf(wsum(u * u)), MIN_NORM);
    float th = tanhf(sc * un);
    float p = th * u / (sc * un);
    float pn = fmaxf(sqrtf(wsum(p * p)), MIN_NORM);
    if (pn > maxnorm) p = p / pn * maxnorm;
    out[(size_t)r * 64 + lane] = p;
  }
}

extern "C" void kernel_launch(void* const* d_in, const int* in_sizes, int n_in,
                              void* d_out, int out_size, void* d_ws, size_t ws_size,
                              hipStream_t stream) {
  const float* x = (const float*)d_in[0];      // [N,256]
  const float* W = (const float*)d_in[1];      // [256,64]
  const float* bias = (const float*)d_in[2];   // [64]
  const float* vals = (const float*)d_in[3];   // [E]
  const float* cptr = (const float*)d_in[4];   // scalar
  const int* row = (const int*)d_in[5];        // [E]
  const int* col = (const int*)d_in[6];        // [E]
  float* out = (float*)d_out;                  // [N,64]
  float* h = (float*)d_ws;                     // [N,64] intermediate

  const int OUT = in_sizes[2];                 // 64
  const int IN = in_sizes[1] / OUT;            // 256
  const int N = in_sizes[0] / IN;              // 50000
  const int E = in_sizes[3];                   // 800000

  // zero the scatter target first (harness poisons d_out with 0xAA)
  hipMemsetAsync(d_out, 0, (size_t)out_size * sizeof(float), stream);

  hyp_linear_kernel<<<512, 256, 0, stream>>>(x, W, bias, cptr, h, N);
  edge_kernel<<<2048, 256, 0, stream>>>(h, vals, row, col, out, E);
  final_kernel<<<1024, 256, 0, stream>>>(out, cptr, N);
}

// Round 5
// 371.378 us; speedup vs baseline: 1.0910x; 1.0910x over previous
//
#include <hip/hip_runtime.h>
#include <math.h>

#define MIN_NORM 1e-15f
#define BALL_EPS 4e-3f

__device__ __forceinline__ float wsum(float v) {
#pragma unroll
  for (int off = 32; off; off >>= 1) v += __shfl_xor(v, off, 64);
  return v;
}

__device__ __forceinline__ float artanh_clip(float z) {
  z = fminf(fmaxf(z, -1.0f + 1e-7f), 1.0f - 1e-7f);
  return 0.5f * (log1pf(z) - log1pf(-z));
}

// Phase 1: per-row  h = logmap0(mobius_add(mobius_matvec(W, x, c), hyp_bias, c), c)
__global__ __launch_bounds__(256) void hyp_linear_kernel(
    const float* __restrict__ x, const float* __restrict__ W,
    const float* __restrict__ bias, const float* __restrict__ cptr,
    float* __restrict__ h, int N) {
  __shared__ float sW[256 * 64];   // 64 KB
  __shared__ float sx[4][256];     // per-wave x row staging
  const int tid = threadIdx.x;
  const int lane = tid & 63;
  const int wid = tid >> 6;
  const float c = *cptr;
  const float sc = sqrtf(c);

  for (int i = tid * 4; i < 256 * 64; i += 1024)
    *(float4*)&sW[i] = *(const float4*)&W[i];

  float b = bias[lane];
  float bnorm = fmaxf(sqrtf(wsum(b * b)), MIN_NORM);
  float tb = tanhf(sc * bnorm);
  float hb = tb * b / (sc * bnorm);
  float hbn = fmaxf(tb / sc, MIN_NORM);
  const float maxnorm = (1.0f - BALL_EPS) / sc;
  if (hbn > maxnorm) hb = hb / hbn * maxnorm;
  const float y2 = wsum(hb * hb);
  __syncthreads();

  const int nwaves = gridDim.x * 4;
  for (int r = blockIdx.x * 4 + wid; r < N; r += nwaves) {
    float4 xv = *(const float4*)&x[(size_t)r * 256 + lane * 4];
    *(float4*)&sx[wid][lane * 4] = xv;
    float x2 = wsum(xv.x * xv.x + xv.y * xv.y + xv.z * xv.z + xv.w * xv.w);
    asm volatile("s_waitcnt lgkmcnt(0)" ::: "memory");

    float acc = 0.0f;
#pragma unroll
    for (int i = 0; i < 256; i += 4) {
      float4 xq = *(const float4*)&sx[wid][i];
      acc = fmaf(xq.x, sW[(i + 0) * 64 + lane], acc);
      acc = fmaf(xq.y, sW[(i + 1) * 64 + lane], acc);
      acc = fmaf(xq.z, sW[(i + 2) * 64 + lane], acc);
      acc = fmaf(xq.w, sW[(i + 3) * 64 + lane], acc);
    }

    float mx = acc;
    int allzero = __all(mx == 0.0f);
    float mx_norm = fmaxf(sqrtf(wsum(mx * mx)), MIN_NORM);
    float x_norm = fmaxf(sqrtf(x2), MIN_NORM);
    float art = artanh_clip(sc * x_norm);
    float t = tanhf(mx_norm / x_norm * art);
    float res = t * mx / (mx_norm * sc);
    if (allzero) res = 0.0f;

    float x2m = wsum(res * res);
    float xy = wsum(res * hb);
    float k = 1.0f + 2.0f * c * xy;
    float num = (k + c * y2) * res + (1.0f - c * x2m) * hb;
    float den = k + c * c * x2m * y2;
    float ma = num / fmaxf(den, MIN_NORM);

    float p_norm = fmaxf(sqrtf(wsum(ma * ma)), MIN_NORM);
    float art2 = artanh_clip(sc * p_norm);
    h[(size_t)r * 64 + lane] = art2 * ma / (sc * p_norm);
  }
}

// ---- CSR build ----
__global__ __launch_bounds__(256) void hist_kernel(const int* __restrict__ row,
                                                   int* __restrict__ cnt, int E) {
  int i = blockIdx.x * blockDim.x + threadIdx.x;
  if (i < E) atomicAdd(&cnt[row[i]], 1);
}

__global__ __launch_bounds__(1024) void scan_a(const int* __restrict__ cnt,
                                               int* __restrict__ rowptr,
                                               int* __restrict__ blksum, int N) {
  __shared__ int wsums[16];
  int gid = blockIdx.x * 1024 + threadIdx.x;
  int lane = threadIdx.x & 63, w = threadIdx.x >> 6;
  int v = (gid < N) ? cnt[gid] : 0;
  int s = v;
#pragma unroll
  for (int d = 1; d < 64; d <<= 1) { int t = __shfl_up(s, d, 64); if (lane >= d) s += t; }
  if (lane == 63) wsums[w] = s;
  __syncthreads();
  if (w == 0 && lane < 16) {
    int ss = wsums[lane];
#pragma unroll
    for (int d = 1; d < 16; d <<= 1) { int u = __shfl_up(ss, d, 64); if (lane >= d) ss += u; }
    wsums[lane] = ss;
  }
  __syncthreads();
  if (w > 0) s += wsums[w - 1];
  if (gid < N) rowptr[1 + gid] = s;
  if (threadIdx.x == 1023) blksum[blockIdx.x] = s;
}

__global__ void scan_b(int* __restrict__ blksum, int nblk) {
  int lane = threadIdx.x;
  int v = (lane < nblk) ? blksum[lane] : 0;
  int s = v;
#pragma unroll
  for (int d = 1; d < 64; d <<= 1) { int t = __shfl_up(s, d, 64); if (lane >= d) s += t; }
  if (lane < nblk) blksum[lane] = s - v;  // exclusive block offsets
}

__global__ __launch_bounds__(1024) void scan_c(int* __restrict__ rowptr,
                                               const int* __restrict__ blksum, int N) {
  int gid = blockIdx.x * 1024 + threadIdx.x;
  if (gid == 0) rowptr[0] = 0;
  if (gid < N) rowptr[1 + gid] += blksum[blockIdx.x];
}

__global__ __launch_bounds__(256) void scatter_kernel(
    const int* __restrict__ row, const int* __restrict__ col,
    const float* __restrict__ vals, const int* __restrict__ rowptr,
    int* __restrict__ cursor, int* __restrict__ scol, float* __restrict__ sval, int E) {
  int i = blockIdx.x * blockDim.x + threadIdx.x;
  if (i < E) {
    int r = row[i];
    int p = atomicAdd(&cursor[r], 1);
    int pos = rowptr[r] + p;
    scol[pos] = col[i];
    sval[pos] = vals[i];
  }
}

// Segmented sum over CSR rows, fused with expmap0 + proj. Wave per row.
__global__ __launch_bounds__(256) void segsum_kernel(
    const float* __restrict__ h, const int* __restrict__ rowptr,
    const int* __restrict__ scol, const float* __restrict__ sval,
    const float* __restrict__ cptr, float* __restrict__ out, int N) {
  const int lane = threadIdx.x & 63;
  const int wid = threadIdx.x >> 6;
  int r = blockIdx.x * 4 + wid;
  if (r >= N) return;
  const float c = *cptr;
  const float sc = sqrtf(c);
  const float maxnorm = (1.0f - BALL_EPS) / sc;
  int st = __builtin_amdgcn_readfirstlane(rowptr[r]);
  int en = __builtin_amdgcn_readfirstlane(rowptr[r + 1]);
  float acc = 0.0f;
  for (int i = st; i < en; ++i) {
    int cc = scol[i];
    float vv = sval[i];
    acc = fmaf(vv, h[(size_t)cc * 64 + lane], acc);
  }
  // out = proj(expmap0(acc, c), c)
  float un = fmaxf(sqrtf(wsum(acc * acc)), MIN_NORM);
  float th = tanhf(sc * un);
  float p = th * acc / (sc * un);
  float pn = fmaxf(sqrtf(wsum(p * p)), MIN_NORM);
  if (pn > maxnorm) p = p / pn * maxnorm;
  out[(size_t)r * 64 + lane] = p;
}

// ---- fallback (old atomic path) ----
__global__ __launch_bounds__(256) void edge_kernel(
    const float* __restrict__ h, const float* __restrict__ vals,
    const int* __restrict__ row, const int* __restrict__ col,
    float* __restrict__ out, int E) {
  const int lane = threadIdx.x & 63;
  const int wid0 = (blockIdx.x * blockDim.x + threadIdx.x) >> 6;
  const int nw = (gridDim.x * blockDim.x) >> 6;
  for (int e = wid0; e < E; e += nw) {
    int eu = __builtin_amdgcn_readfirstlane(e);
    float v = vals[eu];
    int r = row[eu];
    int cl = col[eu];
    atomicAdd(&out[(size_t)r * 64 + lane], v * h[(size_t)cl * 64 + lane]);
  }
}

__global__ __launch_bounds__(256) void final_kernel(
    float* __restrict__ out, const float* __restrict__ cptr, int N) {
  const int lane = threadIdx.x & 63;
  const int wid0 = (blockIdx.x * blockDim.x + threadIdx.x) >> 6;
  const int nw = (gridDim.x * blockDim.x) >> 6;
  const float c = *cptr;
  const float sc = sqrtf(c);
  const float maxnorm = (1.0f - BALL_EPS) / sc;
  for (int r = wid0; r < N; r += nw) {
    float u = out[(size_t)r * 64 + lane];
    float un = fmaxf(sqrtf(wsum(u * u)), MIN_NORM);
    float th = tanhf(sc * un);
    float p = th * u / (sc * un);
    float pn = fmaxf(sqrtf(wsum(p * p)), MIN_NORM);
    if (pn > maxnorm) p = p / pn * maxnorm;
    out[(size_t)r * 64 + lane] = p;
  }
}

static inline size_t align256(size_t x) { return (x + 255) & ~(size_t)255; }

extern "C" void kernel_launch(void* const* d_in, const int* in_sizes, int n_in,
                              void* d_out, int out_size, void* d_ws, size_t ws_size,
                              hipStream_t stream) {
  const float* x = (const float*)d_in[0];      // [N,256]
  const float* W = (const float*)d_in[1];      // [256,64]
  const float* bias = (const float*)d_in[2];   // [64]
  const float* vals = (const float*)d_in[3];   // [E]
  const float* cptr = (const float*)d_in[4];   // scalar
  const int* row = (const int*)d_in[5];        // [E]
  const int* col = (const int*)d_in[6];        // [E]
  float* out = (float*)d_out;                  // [N,64]

  const int OUT = in_sizes[2];                 // 64
  const int IN = in_sizes[1] / OUT;            // 256
  const int N = in_sizes[0] / IN;              // 50000
  const int E = in_sizes[3];                   // 800000

  // ws layout
  char* ws = (char*)d_ws;
  size_t o_h = 0;
  size_t o_rowptr = align256(o_h + (size_t)N * 64 * 4);
  size_t o_blk = align256(o_rowptr + (size_t)(N + 1) * 4);
  size_t o_cursor = align256(o_blk + 64 * 4);
  size_t o_scol = align256(o_cursor + (size_t)N * 4);
  size_t o_sval = align256(o_scol + (size_t)E * 4);
  size_t needed = o_sval + (size_t)E * 4;

  float* h = (float*)(ws + o_h);

  hyp_linear_kernel<<<512, 256, 0, stream>>>(x, W, bias, cptr, h, N);

  if (needed <= ws_size) {
    int* rowptr = (int*)(ws + o_rowptr);
    int* blksum = (int*)(ws + o_blk);
    int* cursor = (int*)(ws + o_cursor);
    int* scol = (int*)(ws + o_scol);
    float* sval = (float*)(ws + o_sval);

    const int nblk = (N + 1023) / 1024;
    const int eb = (E + 255) / 256;

    hipMemsetAsync(cursor, 0, (size_t)N * 4, stream);
    hist_kernel<<<eb, 256, 0, stream>>>(row, cursor, E);
    scan_a<<<nblk, 1024, 0, stream>>>(cursor, rowptr, blksum, N);
    scan_b<<<1, 64, 0, stream>>>(blksum, nblk);
    scan_c<<<nblk, 1024, 0, stream>>>(rowptr, blksum, N);
    hipMemsetAsync(cursor, 0, (size_t)N * 4, stream);
    scatter_kernel<<<eb, 256, 0, stream>>>(row, col, vals, rowptr, cursor, scol, sval, E);
    segsum_kernel<<<(N + 3) / 4, 256, 0, stream>>>(h, rowptr, scol, sval, cptr, out, N);
  } else {
    // fallback: atomic scatter path
    hipMemsetAsync(d_out, 0, (size_t)out_size * sizeof(float), stream);
    edge_kernel<<<2048, 256, 0, stream>>>(h, vals, row, col, out, E);
    final_kernel<<<1024, 256, 0, stream>>>(out, cptr, N);
  }
}

// Round 6
// 301.030 us; speedup vs baseline: 1.3459x; 1.2337x over previous
//
#include <hip/hip_runtime.h>
#include <math.h>

#define MIN_NORM 1e-15f
#define BALL_EPS 4e-3f

typedef __attribute__((ext_vector_type(8))) short bf16x8;
typedef __attribute__((ext_vector_type(4))) float f32x4;

__device__ __forceinline__ short f2bf(float f) {
  unsigned u = __builtin_bit_cast(unsigned, f);
  u = u + 0x7FFFu + ((u >> 16) & 1u);   // RNE
  return (short)(u >> 16);
}
__device__ __forceinline__ float bf2f(unsigned short us) {
  unsigned u = ((unsigned)us) << 16;
  return __builtin_bit_cast(float, u);
}

__device__ __forceinline__ float wsum(float v) {
#pragma unroll
  for (int off = 32; off; off >>= 1) v += __shfl_xor(v, off, 64);
  return v;
}

__device__ __forceinline__ float artanh_clip(float z) {
  z = fminf(fmaxf(z, -1.0f + 1e-7f), 1.0f - 1e-7f);
  return 0.5f * (log1pf(z) - log1pf(-z));
}

// Phase 1 via MFMA: h = logmap0(mobius_add(mobius_matvec(W, x, c), hyp_bias, c), c)
// One wave per 16-row block. A = x rows (16x32 per kk), B = W (32x16 per kk,t).
// mfma_f32_16x16x32_bf16: A lane l: row=l&15, k=(l>>4)*8+j ; B lane l: col=l&15,
// k=(l>>4)*8+j ; D lane l: col=l&15, row=(l>>4)*4+reg  [learn_hip m89 verified].
__global__ __launch_bounds__(256) void hyp_linear_mfma(
    const float* __restrict__ x, const float* __restrict__ W,
    const float* __restrict__ bias, const float* __restrict__ cptr,
    unsigned short* __restrict__ h, int N) {
  const int lane = threadIdx.x & 63;
  const int wid = threadIdx.x >> 6;
  const int m = lane & 15;   // A-row / B-col / D-col
  const int g = lane >> 4;   // k-group (and D row-group)
  const float c = *cptr;
  const float sc = sqrtf(c);
  const float maxnorm = (1.0f - BALL_EPS) / sc;

  // ---- B fragments (loop-invariant, 128 VGPR): b[kk][t][j] = W[kk*32+g*8+j][t*16+m]
  bf16x8 b[8][4];
#pragma unroll
  for (int kk = 0; kk < 8; ++kk)
#pragma unroll
    for (int t = 0; t < 4; ++t) {
      const float* wp = &W[(kk * 32 + g * 8) * 64 + t * 16 + m];
      bf16x8 bb;
#pragma unroll
      for (int j = 0; j < 8; ++j) bb[j] = f2bf(wp[j * 64]);
      b[kk][t] = bb;
    }

  // ---- hyp_bias = proj(expmap0(bias,c),c); per-lane cols n = t*16+m
  float bv[4], bsq = 0.f;
#pragma unroll
  for (int t = 0; t < 4; ++t) { bv[t] = bias[t * 16 + m]; bsq += bv[t] * bv[t]; }
#pragma unroll
  for (int o = 1; o < 16; o <<= 1) bsq += __shfl_xor(bsq, o, 64);
  float bnorm = fmaxf(sqrtf(bsq), MIN_NORM);
  float tb = tanhf(sc * bnorm);
  float bfac = tb / (sc * bnorm);
  float hbn = fmaxf(tb / sc, MIN_NORM);          // == ||hyp_bias|| pre-proj
  float pfac = (hbn > maxnorm) ? (maxnorm / hbn) : 1.0f;
  float hbv[4], y2 = 0.f;
#pragma unroll
  for (int t = 0; t < 4; ++t) { hbv[t] = bv[t] * bfac * pfac; y2 += hbv[t] * hbv[t]; }
#pragma unroll
  for (int o = 1; o < 16; o <<= 1) y2 += __shfl_xor(y2, o, 64);

  const int nb16 = (N + 15) >> 4;
  const int wstep = gridDim.x * 4;
  for (int rb = blockIdx.x * 4 + wid; rb < nb16; rb += wstep) {
    int arow = rb * 16 + m;
    if (arow >= N) arow = N - 1;                 // clamp (N%16==0 normally)
    const float* xp = &x[(size_t)arow * 256 + g * 8];

    // stage A fragments + fp32 ||x||^2 partial
    bf16x8 a[8];
    float x2p = 0.f;
#pragma unroll
    for (int kk = 0; kk < 8; ++kk) {
      float4 v0 = *(const float4*)(xp + kk * 32);
      float4 v1 = *(const float4*)(xp + kk * 32 + 4);
      x2p += v0.x * v0.x + v0.y * v0.y + v0.z * v0.z + v0.w * v0.w +
             v1.x * v1.x + v1.y * v1.y + v1.z * v1.z + v1.w * v1.w;
      bf16x8 aa;
      aa[0] = f2bf(v0.x); aa[1] = f2bf(v0.y); aa[2] = f2bf(v0.z); aa[3] = f2bf(v0.w);
      aa[4] = f2bf(v1.x); aa[5] = f2bf(v1.y); aa[6] = f2bf(v1.z); aa[7] = f2bf(v1.w);
      a[kk] = aa;
    }
    float x2f = x2p;                              // full ||x||^2 of row m
    x2f += __shfl_xor(x2f, 16, 64);
    x2f += __shfl_xor(x2f, 32, 64);

    f32x4 acc[4];
#pragma unroll
    for (int t = 0; t < 4; ++t) { acc[t][0] = 0.f; acc[t][1] = 0.f; acc[t][2] = 0.f; acc[t][3] = 0.f; }
#pragma unroll
    for (int kk = 0; kk < 8; ++kk)
#pragma unroll
      for (int t = 0; t < 4; ++t)
        acc[t] = __builtin_amdgcn_mfma_f32_16x16x32_bf16(a[kk], b[kk][t], acc[t], 0, 0, 0);

    // redistribute x2: epilogue row for (g, reg j) is g*4+j; x2f lives keyed by m
    float x2r[4];
#pragma unroll
    for (int j = 0; j < 4; ++j) x2r[j] = __shfl(x2f, g * 4 + j, 64);

#pragma unroll
    for (int j = 0; j < 4; ++j) {
      float m0 = acc[0][j], m1 = acc[1][j], m2 = acc[2][j], m3 = acc[3][j];
      float msq = m0 * m0 + m1 * m1 + m2 * m2 + m3 * m3;
      int z = (m0 == 0.f) && (m1 == 0.f) && (m2 == 0.f) && (m3 == 0.f);
#pragma unroll
      for (int o = 1; o < 16; o <<= 1) {
        msq += __shfl_xor(msq, o, 64);
        z &= __shfl_xor(z, o, 64);
      }
      float mx_norm = fmaxf(sqrtf(msq), MIN_NORM);
      float x_norm = fmaxf(sqrtf(x2r[j]), MIN_NORM);
      float art = artanh_clip(sc * x_norm);
      float tt = tanhf(mx_norm / x_norm * art);
      float fac = z ? 0.f : (tt / (mx_norm * sc));
      float r0 = m0 * fac, r1 = m1 * fac, r2 = m2 * fac, r3 = m3 * fac;

      // mobius_add(res, hb)
      float x2m = r0 * r0 + r1 * r1 + r2 * r2 + r3 * r3;
      float xy = r0 * hbv[0] + r1 * hbv[1] + r2 * hbv[2] + r3 * hbv[3];
#pragma unroll
      for (int o = 1; o < 16; o <<= 1) {
        x2m += __shfl_xor(x2m, o, 64);
        xy += __shfl_xor(xy, o, 64);
      }
      float k2 = 1.f + 2.f * c * xy;
      float ca = k2 + c * y2;
      float cb = 1.f - c * x2m;
      float inv = 1.f / fmaxf(k2 + c * c * x2m * y2, MIN_NORM);
      float a0 = (ca * r0 + cb * hbv[0]) * inv;
      float a1 = (ca * r1 + cb * hbv[1]) * inv;
      float a2 = (ca * r2 + cb * hbv[2]) * inv;
      float a3 = (ca * r3 + cb * hbv[3]) * inv;

      // logmap0
      float psq = a0 * a0 + a1 * a1 + a2 * a2 + a3 * a3;
#pragma unroll
      for (int o = 1; o < 16; o <<= 1) psq += __shfl_xor(psq, o, 64);
      float p_norm = fmaxf(sqrtf(psq), MIN_NORM);
      float art2 = artanh_clip(sc * p_norm);
      float fac2 = art2 / (sc * p_norm);

      int row = rb * 16 + g * 4 + j;
      if (row < N) {
        unsigned short* hp = &h[(size_t)row * 64 + m];
        hp[0]  = (unsigned short)f2bf(a0 * fac2);
        hp[16] = (unsigned short)f2bf(a1 * fac2);
        hp[32] = (unsigned short)f2bf(a2 * fac2);
        hp[48] = (unsigned short)f2bf(a3 * fac2);
      }
    }
  }
}

// ---- CSR build ----
__global__ __launch_bounds__(256) void hist_kernel(const int* __restrict__ row,
                                                   int* __restrict__ cnt, int E) {
  int i = blockIdx.x * blockDim.x + threadIdx.x;
  if (i < E) atomicAdd(&cnt[row[i]], 1);
}

__global__ __launch_bounds__(1024) void scan_a(const int* __restrict__ cnt,
                                               int* __restrict__ rowptr,
                                               int* __restrict__ blksum, int N) {
  __shared__ int wsums[16];
  int gid = blockIdx.x * 1024 + threadIdx.x;
  int lane = threadIdx.x & 63, w = threadIdx.x >> 6;
  int v = (gid < N) ? cnt[gid] : 0;
  int s = v;
#pragma unroll
  for (int d = 1; d < 64; d <<= 1) { int t = __shfl_up(s, d, 64); if (lane >= d) s += t; }
  if (lane == 63) wsums[w] = s;
  __syncthreads();
  if (w == 0 && lane < 16) {
    int ss = wsums[lane];
#pragma unroll
    for (int d = 1; d < 16; d <<= 1) { int u = __shfl_up(ss, d, 64); if (lane >= d) ss += u; }
    wsums[lane] = ss;
  }
  __syncthreads();
  if (w > 0) s += wsums[w - 1];
  if (gid < N) rowptr[1 + gid] = s;
  if (threadIdx.x == 1023) blksum[blockIdx.x] = s;
}

__global__ void scan_b(int* __restrict__ blksum, int nblk) {
  int lane = threadIdx.x;
  int v = (lane < nblk) ? blksum[lane] : 0;
  int s = v;
#pragma unroll
  for (int d = 1; d < 64; d <<= 1) { int t = __shfl_up(s, d, 64); if (lane >= d) s += t; }
  if (lane < nblk) blksum[lane] = s - v;  // exclusive block offsets
}

__global__ __launch_bounds__(1024) void scan_c(int* __restrict__ rowptr,
                                               const int* __restrict__ blksum, int N) {
  int gid = blockIdx.x * 1024 + threadIdx.x;
  if (gid == 0) rowptr[0] = 0;
  if (gid < N) rowptr[1 + gid] += blksum[blockIdx.x];
}

// scatter uses rowptr itself as the cursor: after this, rowptr[r] == old rowptr[r+1]
__global__ __launch_bounds__(256) void scatter_kernel(
    const int* __restrict__ row, const int* __restrict__ col,
    const float* __restrict__ vals, int* __restrict__ rowptr,
    int* __restrict__ scol, float* __restrict__ sval, int E) {
  int i = blockIdx.x * blockDim.x + threadIdx.x;
  if (i < E) {
    int r = row[i];
    int pos = atomicAdd(&rowptr[r], 1);
    scol[pos] = col[i];
    sval[pos] = vals[i];
  }
}

// Segmented sum over CSR rows (bf16 h gather), fused with expmap0 + proj.
__global__ __launch_bounds__(256) void segsum_kernel(
    const unsigned short* __restrict__ h, const int* __restrict__ rowptr,
    const int* __restrict__ scol, const float* __restrict__ sval,
    const float* __restrict__ cptr, float* __restrict__ out, int N) {
  const int lane = threadIdx.x & 63;
  const int wid = threadIdx.x >> 6;
  int r = blockIdx.x * 4 + wid;
  if (r >= N) return;
  const float c = *cptr;
  const float sc = sqrtf(c);
  const float maxnorm = (1.0f - BALL_EPS) / sc;
  int st = (r > 0) ? __builtin_amdgcn_readfirstlane(rowptr[r - 1]) : 0;
  int en = __builtin_amdgcn_readfirstlane(rowptr[r]);
  float acc = 0.0f;
  for (int i = st; i < en; ++i) {
    int cc = scol[i];
    float vv = sval[i];
    acc = fmaf(vv, bf2f(h[(size_t)cc * 64 + lane]), acc);
  }
  float un = fmaxf(sqrtf(wsum(acc * acc)), MIN_NORM);
  float th = tanhf(sc * un);
  float p = th * acc / (sc * un);
  float pn = fmaxf(sqrtf(wsum(p * p)), MIN_NORM);
  if (pn > maxnorm) p = p / pn * maxnorm;
  out[(size_t)r * 64 + lane] = p;
}

// ---- fallback (atomic path, bf16 h) ----
__global__ __launch_bounds__(256) void edge_kernel(
    const unsigned short* __restrict__ h, const float* __restrict__ vals,
    const int* __restrict__ row, const int* __restrict__ col,
    float* __restrict__ out, int E) {
  const int lane = threadIdx.x & 63;
  const int wid0 = (blockIdx.x * blockDim.x + threadIdx.x) >> 6;
  const int nw = (gridDim.x * blockDim.x) >> 6;
  for (int e = wid0; e < E; e += nw) {
    int eu = __builtin_amdgcn_readfirstlane(e);
    float v = vals[eu];
    int r = row[eu];
    int cl = col[eu];
    atomicAdd(&out[(size_t)r * 64 + lane], v * bf2f(h[(size_t)cl * 64 + lane]));
  }
}

__global__ __launch_bounds__(256) void final_kernel(
    float* __restrict__ out, const float* __restrict__ cptr, int N) {
  const int lane = threadIdx.x & 63;
  const int wid0 = (blockIdx.x * blockDim.x + threadIdx.x) >> 6;
  const int nw = (gridDim.x * blockDim.x) >> 6;
  const float c = *cptr;
  const float sc = sqrtf(c);
  const float maxnorm = (1.0f - BALL_EPS) / sc;
  for (int r = wid0; r < N; r += nw) {
    float u = out[(size_t)r * 64 + lane];
    float un = fmaxf(sqrtf(wsum(u * u)), MIN_NORM);
    float th = tanhf(sc * un);
    float p = th * u / (sc * un);
    float pn = fmaxf(sqrtf(wsum(p * p)), MIN_NORM);
    if (pn > maxnorm) p = p / pn * maxnorm;
    out[(size_t)r * 64 + lane] = p;
  }
}

static inline size_t align256(size_t x) { return (x + 255) & ~(size_t)255; }

extern "C" void kernel_launch(void* const* d_in, const int* in_sizes, int n_in,
                              void* d_out, int out_size, void* d_ws, size_t ws_size,
                              hipStream_t stream) {
  const float* x = (const float*)d_in[0];      // [N,256]
  const float* W = (const float*)d_in[1];      // [256,64]
  const float* bias = (const float*)d_in[2];   // [64]
  const float* vals = (const float*)d_in[3];   // [E]
  const float* cptr = (const float*)d_in[4];   // scalar
  const int* row = (const int*)d_in[5];        // [E]
  const int* col = (const int*)d_in[6];        // [E]
  float* out = (float*)d_out;                  // [N,64]

  const int OUT = in_sizes[2];                 // 64
  const int IN = in_sizes[1] / OUT;            // 256
  const int N = in_sizes[0] / IN;              // 50000
  const int E = in_sizes[3];                   // 800000

  // ws layout: h(bf16) | rowptr | blksum | cnt | scol | sval
  char* ws = (char*)d_ws;
  size_t o_h = 0;
  size_t o_rowptr = align256(o_h + (size_t)N * 64 * 2);
  size_t o_blk = align256(o_rowptr + (size_t)(N + 1) * 4);
  size_t o_cnt = align256(o_blk + 64 * 4);
  size_t o_scol = align256(o_cnt + (size_t)N * 4);
  size_t o_sval = align256(o_scol + (size_t)E * 4);
  size_t needed = o_sval + (size_t)E * 4;

  unsigned short* h = (unsigned short*)(ws + o_h);

  const int nb16 = (N + 15) / 16;
  const int gblocks = (nb16 + 7) / 8;          // 2 row-blocks per wave
  hyp_linear_mfma<<<gblocks, 256, 0, stream>>>(x, W, bias, cptr, h, N);

  if (needed <= ws_size) {
    int* rowptr = (int*)(ws + o_rowptr);
    int* blksum = (int*)(ws + o_blk);
    int* cnt = (int*)(ws + o_cnt);
    int* scol = (int*)(ws + o_scol);
    float* sval = (float*)(ws + o_sval);

    const int nblk = (N + 1023) / 1024;
    const int eb = (E + 255) / 256;

    hipMemsetAsync(cnt, 0, (size_t)N * 4, stream);
    hist_kernel<<<eb, 256, 0, stream>>>(row, cnt, E);
    scan_a<<<nblk, 1024, 0, stream>>>(cnt, rowptr, blksum, N);
    scan_b<<<1, 64, 0, stream>>>(blksum, nblk);
    scan_c<<<nblk, 1024, 0, stream>>>(rowptr, blksum, N);
    scatter_kernel<<<eb, 256, 0, stream>>>(row, col, vals, rowptr, scol, sval, E);
    segsum_kernel<<<(N + 3) / 4, 256, 0, stream>>>(h, rowptr, scol, sval, cptr, out, N);
  } else {
    hipMemsetAsync(d_out, 0, (size_t)out_size * sizeof(float), stream);
    edge_kernel<<<2048, 256, 0, stream>>>(h, vals, row, col, out, E);
    final_kernel<<<1024, 256, 0, stream>>>(out, cptr, N);
  }
}

// Round 10
// 228.607 us; speedup vs baseline: 1.7723x; 1.3168x over previous
//
#include <hip/hip_runtime.h>
#include <math.h>

#define MIN_NORM 1e-15f
#define BALL_EPS 4e-3f

typedef __attribute__((ext_vector_type(8))) short bf16x8;
typedef __attribute__((ext_vector_type(4))) float f32x4;

__device__ __forceinline__ short f2bf(float f) {
  unsigned u = __builtin_bit_cast(unsigned, f);
  u = u + 0x7FFFu + ((u >> 16) & 1u);   // RNE
  return (short)(u >> 16);
}
__device__ __forceinline__ float bf2f(unsigned short us) {
  unsigned u = ((unsigned)us) << 16;
  return __builtin_bit_cast(float, u);
}

__device__ __forceinline__ float wsum(float v) {
#pragma unroll
  for (int off = 32; off; off >>= 1) v += __shfl_xor(v, off, 64);
  return v;
}

__device__ __forceinline__ float artanh_clip(float z) {
  z = fminf(fmaxf(z, -1.0f + 1e-7f), 1.0f - 1e-7f);
  return 0.5f * (log1pf(z) - log1pf(-z));
}

// K1: blocks [0,G1) do the MFMA hyperbolic linear; blocks [G1,grid) histogram `row`.
__global__ __launch_bounds__(256) void k1_hyp_hist(
    const float* __restrict__ x, const float* __restrict__ W,
    const float* __restrict__ bias, const float* __restrict__ cptr,
    unsigned short* __restrict__ h, int N,
    const int* __restrict__ row, int* __restrict__ cnt, int E, int G1) {
  if ((int)blockIdx.x >= G1) {
    // ---- histogram part ----
    const int nb = gridDim.x - G1;
    for (int i = (blockIdx.x - G1) * 256 + threadIdx.x; i < E; i += nb * 256)
      atomicAdd(&cnt[row[i]], 1);
    return;
  }
  // ---- hyp linear part (MFMA 16x16x32 bf16) ----
  const int lane = threadIdx.x & 63;
  const int wid = threadIdx.x >> 6;
  const int m = lane & 15;   // A-row / B-col / D-col
  const int g = lane >> 4;   // k-group / D row-group
  const float c = *cptr;
  const float sc = sqrtf(c);
  const float maxnorm = (1.0f - BALL_EPS) / sc;

  // B fragments (loop-invariant): b[kk][t][j] = W[kk*32+g*8+j][t*16+m]
  bf16x8 b[8][4];
#pragma unroll
  for (int kk = 0; kk < 8; ++kk)
#pragma unroll
    for (int t = 0; t < 4; ++t) {
      const float* wp = &W[(kk * 32 + g * 8) * 64 + t * 16 + m];
      bf16x8 bb;
#pragma unroll
      for (int j = 0; j < 8; ++j) bb[j] = f2bf(wp[j * 64]);
      b[kk][t] = bb;
    }

  // hyp_bias = proj(expmap0(bias,c),c); per-lane cols n = t*16+m
  float bv[4], bsq = 0.f;
#pragma unroll
  for (int t = 0; t < 4; ++t) { bv[t] = bias[t * 16 + m]; bsq += bv[t] * bv[t]; }
#pragma unroll
  for (int o = 1; o < 16; o <<= 1) bsq += __shfl_xor(bsq, o, 64);
  float bnorm = fmaxf(sqrtf(bsq), MIN_NORM);
  float tb = tanhf(sc * bnorm);
  float bfac = tb / (sc * bnorm);
  float hbn = fmaxf(tb / sc, MIN_NORM);
  float pfac = (hbn > maxnorm) ? (maxnorm / hbn) : 1.0f;
  float hbv[4], y2 = 0.f;
#pragma unroll
  for (int t = 0; t < 4; ++t) { hbv[t] = bv[t] * bfac * pfac; y2 += hbv[t] * hbv[t]; }
#pragma unroll
  for (int o = 1; o < 16; o <<= 1) y2 += __shfl_xor(y2, o, 64);

  const int nb16 = (N + 15) >> 4;
  const int wstep = G1 * 4;
  for (int rb = blockIdx.x * 4 + wid; rb < nb16; rb += wstep) {
    int arow = rb * 16 + m;
    if (arow >= N) arow = N - 1;
    const float* xp = &x[(size_t)arow * 256 + g * 8];

    bf16x8 a[8];
    float x2p = 0.f;
#pragma unroll
    for (int kk = 0; kk < 8; ++kk) {
      float4 v0 = *(const float4*)(xp + kk * 32);
      float4 v1 = *(const float4*)(xp + kk * 32 + 4);
      x2p += v0.x * v0.x + v0.y * v0.y + v0.z * v0.z + v0.w * v0.w +
             v1.x * v1.x + v1.y * v1.y + v1.z * v1.z + v1.w * v1.w;
      bf16x8 aa;
      aa[0] = f2bf(v0.x); aa[1] = f2bf(v0.y); aa[2] = f2bf(v0.z); aa[3] = f2bf(v0.w);
      aa[4] = f2bf(v1.x); aa[5] = f2bf(v1.y); aa[6] = f2bf(v1.z); aa[7] = f2bf(v1.w);
      a[kk] = aa;
    }
    float x2f = x2p;
    x2f += __shfl_xor(x2f, 16, 64);
    x2f += __shfl_xor(x2f, 32, 64);

    f32x4 acc[4];
#pragma unroll
    for (int t = 0; t < 4; ++t) { acc[t][0] = 0.f; acc[t][1] = 0.f; acc[t][2] = 0.f; acc[t][3] = 0.f; }
#pragma unroll
    for (int kk = 0; kk < 8; ++kk)
#pragma unroll
      for (int t = 0; t < 4; ++t)
        acc[t] = __builtin_amdgcn_mfma_f32_16x16x32_bf16(a[kk], b[kk][t], acc[t], 0, 0, 0);

    float x2r[4];
#pragma unroll
    for (int j = 0; j < 4; ++j) x2r[j] = __shfl(x2f, g * 4 + j, 64);

#pragma unroll
    for (int j = 0; j < 4; ++j) {
      float m0 = acc[0][j], m1 = acc[1][j], m2 = acc[2][j], m3 = acc[3][j];
      float msq = m0 * m0 + m1 * m1 + m2 * m2 + m3 * m3;
      int z = (m0 == 0.f) && (m1 == 0.f) && (m2 == 0.f) && (m3 == 0.f);
#pragma unroll
      for (int o = 1; o < 16; o <<= 1) {
        msq += __shfl_xor(msq, o, 64);
        z &= __shfl_xor(z, o, 64);
      }
      float mx_norm = fmaxf(sqrtf(msq), MIN_NORM);
      float x_norm = fmaxf(sqrtf(x2r[j]), MIN_NORM);
      float art = artanh_clip(sc * x_norm);
      float tt = tanhf(mx_norm / x_norm * art);
      float fac = z ? 0.f : (tt / (mx_norm * sc));
      float r0 = m0 * fac, r1 = m1 * fac, r2 = m2 * fac, r3 = m3 * fac;

      float x2m = r0 * r0 + r1 * r1 + r2 * r2 + r3 * r3;
      float xy = r0 * hbv[0] + r1 * hbv[1] + r2 * hbv[2] + r3 * hbv[3];
#pragma unroll
      for (int o = 1; o < 16; o <<= 1) {
        x2m += __shfl_xor(x2m, o, 64);
        xy += __shfl_xor(xy, o, 64);
      }
      float k2 = 1.f + 2.f * c * xy;
      float ca = k2 + c * y2;
      float cb = 1.f - c * x2m;
      float inv = 1.f / fmaxf(k2 + c * c * x2m * y2, MIN_NORM);
      float a0 = (ca * r0 + cb * hbv[0]) * inv;
      float a1 = (ca * r1 + cb * hbv[1]) * inv;
      float a2 = (ca * r2 + cb * hbv[2]) * inv;
      float a3 = (ca * r3 + cb * hbv[3]) * inv;

      float psq = a0 * a0 + a1 * a1 + a2 * a2 + a3 * a3;
#pragma unroll
      for (int o = 1; o < 16; o <<= 1) psq += __shfl_xor(psq, o, 64);
      float p_norm = fmaxf(sqrtf(psq), MIN_NORM);
      float art2 = artanh_clip(sc * p_norm);
      float fac2 = art2 / (sc * p_norm);

      int orow = rb * 16 + g * 4 + j;
      if (orow < N) {
        unsigned short* hp = &h[(size_t)orow * 64 + m];
        hp[0]  = (unsigned short)f2bf(a0 * fac2);
        hp[16] = (unsigned short)f2bf(a1 * fac2);
        hp[32] = (unsigned short)f2bf(a2 * fac2);
        hp[48] = (unsigned short)f2bf(a3 * fac2);
      }
    }
  }
}

// scan_a: per-block inclusive scan of cnt -> rowptr[1+gid]; blksum[b] = block total
__global__ __launch_bounds__(1024) void scan_a(const int* __restrict__ cnt,
                                               int* __restrict__ rowptr,
                                               int* __restrict__ blksum, int N) {
  __shared__ int wsums[16];
  int gid = blockIdx.x * 1024 + threadIdx.x;
  int lane = threadIdx.x & 63, w = threadIdx.x >> 6;
  int v = (gid < N) ? cnt[gid] : 0;
  int s = v;
#pragma unroll
  for (int d = 1; d < 64; d <<= 1) { int t = __shfl_up(s, d, 64); if (lane >= d) s += t; }
  if (lane == 63) wsums[w] = s;
  __syncthreads();
  if (w == 0 && lane < 16) {
    int ss = wsums[lane];
#pragma unroll
    for (int d = 1; d < 16; d <<= 1) { int u = __shfl_up(ss, d, 64); if (lane >= d) ss += u; }
    wsums[lane] = ss;
  }
  __syncthreads();
  if (w > 0) s += wsums[w - 1];
  if (gid < N) rowptr[1 + gid] = s;
  if (threadIdx.x == 1023) blksum[blockIdx.x] = s;
}

// scan_c: each block computes its own exclusive block offset from raw blksum, applies it
__global__ __launch_bounds__(1024) void scan_c(int* __restrict__ rowptr,
                                               const int* __restrict__ blksum,
                                               int N, int nblk) {
  __shared__ int s_off;
  if (threadIdx.x < 64) {
    int acc = 0;
    for (int bidx = threadIdx.x; bidx < (int)blockIdx.x; bidx += 64) acc += blksum[bidx];
#pragma unroll
    for (int off = 32; off; off >>= 1) acc += __shfl_xor(acc, off, 64);
    if (threadIdx.x == 0) s_off = acc;
  }
  __syncthreads();
  int gid = blockIdx.x * 1024 + threadIdx.x;
  if (gid == 0) rowptr[0] = 0;
  if (gid < N) rowptr[1 + gid] += s_off;
}

// scatter: rowptr doubles as cursor; packs (col, val) into int2
__global__ __launch_bounds__(256) void scatter_kernel(
    const int* __restrict__ row, const int* __restrict__ col,
    const float* __restrict__ vals, int* __restrict__ rowptr,
    int2* __restrict__ pairs, int E) {
  int i = blockIdx.x * blockDim.x + threadIdx.x;
  if (i < E) {
    int r = row[i];
    int pos = atomicAdd(&rowptr[r], 1);
    pairs[pos] = make_int2(col[i], __builtin_bit_cast(int, vals[i]));
  }
}

// segsum: wave per row, 4 subwaves x 16 lanes; each subwave one edge, each lane ushort4.
// Fused expmap0 + proj.
__global__ __launch_bounds__(256) void segsum_kernel(
    const unsigned short* __restrict__ h, const int* __restrict__ rowptr,
    const int2* __restrict__ pairs, const float* __restrict__ cptr,
    float* __restrict__ out, int N) {
  const int lane = threadIdx.x & 63;
  const int wid = threadIdx.x >> 6;
  const int sw = lane >> 4;   // subwave 0..3 (edge slot)
  const int q = lane & 15;    // dim quad
  int r = blockIdx.x * 4 + wid;
  if (r >= N) return;
  const float c = *cptr;
  const float sc = sqrtf(c);
  const float maxnorm = (1.0f - BALL_EPS) / sc;
  int st = (r > 0) ? rowptr[r - 1] : 0;
  int en = rowptr[r];
  st = __builtin_amdgcn_readfirstlane(st);
  en = __builtin_amdgcn_readfirstlane(en);

  float a0 = 0.f, a1 = 0.f, a2 = 0.f, a3 = 0.f;
#pragma unroll 2
  for (int i = st + sw; i < en; i += 4) {
    int2 pv = pairs[i];
    float vv = __builtin_bit_cast(float, pv.y);
    ushort4 hv = *(const ushort4*)&h[(size_t)pv.x * 64 + q * 4];
    a0 = fmaf(vv, bf2f(hv.x), a0);
    a1 = fmaf(vv, bf2f(hv.y), a1);
    a2 = fmaf(vv, bf2f(hv.z), a2);
    a3 = fmaf(vv, bf2f(hv.w), a3);
  }
  // combine the 4 subwave partials (all lanes end with full sums)
  a0 += __shfl_xor(a0, 32, 64); a1 += __shfl_xor(a1, 32, 64);
  a2 += __shfl_xor(a2, 32, 64); a3 += __shfl_xor(a3, 32, 64);
  a0 += __shfl_xor(a0, 16, 64); a1 += __shfl_xor(a1, 16, 64);
  a2 += __shfl_xor(a2, 16, 64); a3 += __shfl_xor(a3, 16, 64);

  float sq = a0 * a0 + a1 * a1 + a2 * a2 + a3 * a3;
#pragma unroll
  for (int o = 1; o < 16; o <<= 1) sq += __shfl_xor(sq, o, 64);
  float un = fmaxf(sqrtf(sq), MIN_NORM);
  float th = tanhf(sc * un);
  float fac = th / (sc * un);
  float p0 = a0 * fac, p1 = a1 * fac, p2 = a2 * fac, p3 = a3 * fac;
  float psq = p0 * p0 + p1 * p1 + p2 * p2 + p3 * p3;
#pragma unroll
  for (int o = 1; o < 16; o <<= 1) psq += __shfl_xor(psq, o, 64);
  float pn = fmaxf(sqrtf(psq), MIN_NORM);
  if (pn > maxnorm) {
    float pf = maxnorm / pn;
    p0 *= pf; p1 *= pf; p2 *= pf; p3 *= pf;
  }
  if (sw == 0)
    *(float4*)&out[(size_t)r * 64 + q * 4] = make_float4(p0, p1, p2, p3);
}

// ---- fallback (atomic path, bf16 h) ----
__global__ __launch_bounds__(256) void edge_kernel(
    const unsigned short* __restrict__ h, const float* __restrict__ vals,
    const int* __restrict__ row, const int* __restrict__ col,
    float* __restrict__ out, int E) {
  const int lane = threadIdx.x & 63;
  const int wid0 = (blockIdx.x * blockDim.x + threadIdx.x) >> 6;
  const int nw = (gridDim.x * blockDim.x) >> 6;
  for (int e = wid0; e < E; e += nw) {
    int eu = __builtin_amdgcn_readfirstlane(e);
    float v = vals[eu];
    int r = row[eu];
    int cl = col[eu];
    atomicAdd(&out[(size_t)r * 64 + lane], v * bf2f(h[(size_t)cl * 64 + lane]));
  }
}

__global__ __launch_bounds__(256) void final_kernel(
    float* __restrict__ out, const float* __restrict__ cptr, int N) {
  const int lane = threadIdx.x & 63;
  const int wid0 = (blockIdx.x * blockDim.x + threadIdx.x) >> 6;
  const int nw = (gridDim.x * blockDim.x) >> 6;
  const float c = *cptr;
  const float sc = sqrtf(c);
  const float maxnorm = (1.0f - BALL_EPS) / sc;
  for (int r = wid0; r < N; r += nw) {
    float u = out[(size_t)r * 64 + lane];
    float un = fmaxf(sqrtf(wsum(u * u)), MIN_NORM);
    float th = tanhf(sc * un);
    float p = th * u / (sc * un);
    float pn = fmaxf(sqrtf(wsum(p * p)), MIN_NORM);
    if (pn > maxnorm) p = p / pn * maxnorm;
    out[(size_t)r * 64 + lane] = p;
  }
}

static inline size_t align256(size_t x) { return (x + 255) & ~(size_t)255; }

extern "C" void kernel_launch(void* const* d_in, const int* in_sizes, int n_in,
                              void* d_out, int out_size, void* d_ws, size_t ws_size,
                              hipStream_t stream) {
  const float* x = (const float*)d_in[0];      // [N,256]
  const float* W = (const float*)d_in[1];      // [256,64]
  const float* bias = (const float*)d_in[2];   // [64]
  const float* vals = (const float*)d_in[3];   // [E]
  const float* cptr = (const float*)d_in[4];   // scalar
  const int* row = (const int*)d_in[5];        // [E]
  const int* col = (const int*)d_in[6];        // [E]
  float* out = (float*)d_out;                  // [N,64]

  const int OUT = in_sizes[2];                 // 64
  const int IN = in_sizes[1] / OUT;            // 256
  const int N = in_sizes[0] / IN;              // 50000
  const int E = in_sizes[3];                   // 800000

  // ws layout: h(bf16) | rowptr | blksum | cnt | pairs(int2)
  char* ws = (char*)d_ws;
  size_t o_h = 0;
  size_t o_rowptr = align256(o_h + (size_t)N * 64 * 2);
  size_t o_blk = align256(o_rowptr + (size_t)(N + 1) * 4);
  size_t o_cnt = align256(o_blk + 1024 * 4);
  size_t o_pairs = align256(o_cnt + (size_t)N * 4);
  size_t needed = o_pairs + (size_t)E * 8;

  unsigned short* h = (unsigned short*)(ws + o_h);

  const int nb16 = (N + 15) / 16;
  const int G1 = (nb16 + 7) / 8;               // hyp blocks (2 row-blocks per wave)

  if (needed <= ws_size) {
    int* rowptr = (int*)(ws + o_rowptr);
    int* blksum = (int*)(ws + o_blk);
    int* cnt = (int*)(ws + o_cnt);
    int2* pairs = (int2*)(ws + o_pairs);

    const int nblk = (N + 1023) / 1024;
    const int eb = (E + 255) / 256;
    const int HB = 256;                        // histogram blocks

    hipMemsetAsync(cnt, 0, (size_t)N * 4, stream);
    k1_hyp_hist<<<G1 + HB, 256, 0, stream>>>(x, W, bias, cptr, h, N, row, cnt, E, G1);
    scan_a<<<nblk, 1024, 0, stream>>>(cnt, rowptr, blksum, N);
    scan_c<<<nblk, 1024, 0, stream>>>(rowptr, blksum, N, nblk);
    scatter_kernel<<<eb, 256, 0, stream>>>(row, col, vals, rowptr, pairs, E);
    segsum_kernel<<<(N + 3) / 4, 256, 0, stream>>>(h, rowptr, pairs, cptr, out, N);
  } else {
    // fallback: atomic scatter path (h only in ws)
    k1_hyp_hist<<<G1, 256, 0, stream>>>(x, W, bias, cptr, h, N, row, (int*)nullptr, 0, G1);
    hipMemsetAsync(d_out, 0, (size_t)out_size * sizeof(float), stream);
    edge_kernel<<<2048, 256, 0, stream>>>(h, vals, row, col, out, E);
    final_kernel<<<1024, 256, 0, stream>>>(out, cptr, N);
  }
}

// Round 12
// 227.265 us; speedup vs baseline: 1.7827x; 1.0059x over previous
//
#include <hip/hip_runtime.h>
#include <math.h>

#define MIN_NORM 1e-15f
#define BALL_EPS 4e-3f

typedef __attribute__((ext_vector_type(8))) short bf16x8;
typedef __attribute__((ext_vector_type(4))) float f32x4;

__device__ __forceinline__ short f2bf(float f) {
  unsigned u = __builtin_bit_cast(unsigned, f);
  u = u + 0x7FFFu + ((u >> 16) & 1u);   // RNE
  return (short)(u >> 16);
}
__device__ __forceinline__ float bf2f(unsigned short us) {
  unsigned u = ((unsigned)us) << 16;
  return __builtin_bit_cast(float, u);
}

__device__ __forceinline__ float wsum(float v) {
#pragma unroll
  for (int off = 32; off; off >>= 1) v += __shfl_xor(v, off, 64);
  return v;
}

__device__ __forceinline__ float artanh_clip(float z) {
  z = fminf(fmaxf(z, -1.0f + 1e-7f), 1.0f - 1e-7f);
  return 0.5f * (log1pf(z) - log1pf(-z));
}

// K1: blocks [0,G1) = pure MFMA GEMM (mx = x@W, plus x2 = ||x_row||^2);
//     blocks [G1,..) = histogram of `row`.
__global__ __launch_bounds__(256) void k1_gemm_hist(
    const float* __restrict__ x, const float* __restrict__ W,
    float* __restrict__ mx_ws, float* __restrict__ x2_ws, int N,
    const int* __restrict__ row, int* __restrict__ cnt, int E, int G1) {
  if ((int)blockIdx.x >= G1) {
    const int nb = gridDim.x - G1;
    for (int i = (blockIdx.x - G1) * 256 + threadIdx.x; i < E; i += nb * 256)
      atomicAdd(&cnt[row[i]], 1);
    return;
  }
  const int lane = threadIdx.x & 63;
  const int wid = threadIdx.x >> 6;
  const int m = lane & 15;   // A-row / D-col
  const int g = lane >> 4;   // k-group / D row-group

  // B fragments (loop-invariant): b[kk][t][j] = W[kk*32+g*8+j][t*16+m]
  bf16x8 b[8][4];
#pragma unroll
  for (int kk = 0; kk < 8; ++kk)
#pragma unroll
    for (int t = 0; t < 4; ++t) {
      const float* wp = &W[(kk * 32 + g * 8) * 64 + t * 16 + m];
      bf16x8 bb;
#pragma unroll
      for (int j = 0; j < 8; ++j) bb[j] = f2bf(wp[j * 64]);
      b[kk][t] = bb;
    }

  const int nb16 = (N + 15) >> 4;
  const int wstep = G1 * 4;
  for (int rb = blockIdx.x * 4 + wid; rb < nb16; rb += wstep) {
    int arow = rb * 16 + m;
    if (arow >= N) arow = N - 1;
    const float* xp = &x[(size_t)arow * 256 + g * 8];

    bf16x8 a[8];
    float x2p = 0.f;
#pragma unroll
    for (int kk = 0; kk < 8; ++kk) {
      float4 v0 = *(const float4*)(xp + kk * 32);
      float4 v1 = *(const float4*)(xp + kk * 32 + 4);
      x2p += v0.x * v0.x + v0.y * v0.y + v0.z * v0.z + v0.w * v0.w +
             v1.x * v1.x + v1.y * v1.y + v1.z * v1.z + v1.w * v1.w;
      bf16x8 aa;
      aa[0] = f2bf(v0.x); aa[1] = f2bf(v0.y); aa[2] = f2bf(v0.z); aa[3] = f2bf(v0.w);
      aa[4] = f2bf(v1.x); aa[5] = f2bf(v1.y); aa[6] = f2bf(v1.z); aa[7] = f2bf(v1.w);
      a[kk] = aa;
    }
    float x2f = x2p;
    x2f += __shfl_xor(x2f, 16, 64);
    x2f += __shfl_xor(x2f, 32, 64);

    f32x4 acc[4];
#pragma unroll
    for (int t = 0; t < 4; ++t) { acc[t][0] = 0.f; acc[t][1] = 0.f; acc[t][2] = 0.f; acc[t][3] = 0.f; }
#pragma unroll
    for (int kk = 0; kk < 8; ++kk)
#pragma unroll
      for (int t = 0; t < 4; ++t)
        acc[t] = __builtin_amdgcn_mfma_f32_16x16x32_bf16(a[kk], b[kk][t], acc[t], 0, 0, 0);

    // store mx (D layout: row = g*4+j, col = t*16+m) and x2 (keyed by m)
#pragma unroll
    for (int j = 0; j < 4; ++j) {
      int orow = rb * 16 + g * 4 + j;
      if (orow < N) {
        float* mp = &mx_ws[(size_t)orow * 64 + m];
#pragma unroll
        for (int t = 0; t < 4; ++t) mp[t * 16] = acc[t][j];
      }
    }
    if (g == 0 && rb * 16 + m < N) x2_ws[rb * 16 + m] = x2f;
  }
}

// K1b: hyperbolic per-row math. 4 rows per wave (16-lane groups, float4 per lane).
// h = logmap0(mobius_add(res_c(mx, x2), hyp_bias, c), c)  -> bf16
__global__ __launch_bounds__(256) void k1b_hyp(
    const float* __restrict__ mx_ws, const float* __restrict__ x2_ws,
    const float* __restrict__ bias, const float* __restrict__ cptr,
    unsigned short* __restrict__ h, int N) {
  const int lane = threadIdx.x & 63;
  const int wid = threadIdx.x >> 6;
  const int sub = lane >> 4;   // row slot 0..3
  const int q = lane & 15;     // dim quad
  const float c = *cptr;
  const float sc = sqrtf(c);
  const float maxnorm = (1.0f - BALL_EPS) / sc;

  // hyp_bias = proj(expmap0(bias,c),c): lane holds dims q*4..q*4+3
  float4 bv = *(const float4*)&bias[q * 4];
  float bsq = bv.x * bv.x + bv.y * bv.y + bv.z * bv.z + bv.w * bv.w;
#pragma unroll
  for (int o = 1; o < 16; o <<= 1) bsq += __shfl_xor(bsq, o, 64);
  float bnorm = fmaxf(sqrtf(bsq), MIN_NORM);
  float tb = tanhf(sc * bnorm);
  float bfac = tb / (sc * bnorm);
  float hbn = fmaxf(tb / sc, MIN_NORM);
  float pfac = (hbn > maxnorm) ? (maxnorm / hbn) : 1.0f;
  float hb0 = bv.x * bfac * pfac, hb1 = bv.y * bfac * pfac;
  float hb2 = bv.z * bfac * pfac, hb3 = bv.w * bfac * pfac;
  float y2 = hb0 * hb0 + hb1 * hb1 + hb2 * hb2 + hb3 * hb3;
#pragma unroll
  for (int o = 1; o < 16; o <<= 1) y2 += __shfl_xor(y2, o, 64);

  const int r = (blockIdx.x * 4 + wid) * 4 + sub;
  if (r >= N) return;  // uniform per 16-lane group

  float4 mv = *(const float4*)&mx_ws[(size_t)r * 64 + q * 4];
  float x2v = x2_ws[r];

  float msq = mv.x * mv.x + mv.y * mv.y + mv.z * mv.z + mv.w * mv.w;
  int z = (mv.x == 0.f) && (mv.y == 0.f) && (mv.z == 0.f) && (mv.w == 0.f);
#pragma unroll
  for (int o = 1; o < 16; o <<= 1) {
    msq += __shfl_xor(msq, o, 64);
    z &= __shfl_xor(z, o, 64);
  }
  float mx_norm = fmaxf(sqrtf(msq), MIN_NORM);
  float x_norm = fmaxf(sqrtf(x2v), MIN_NORM);
  float art = artanh_clip(sc * x_norm);
  float tt = tanhf(mx_norm / x_norm * art);
  float fac = z ? 0.f : (tt / (mx_norm * sc));
  float r0 = mv.x * fac, r1 = mv.y * fac, r2 = mv.z * fac, r3 = mv.w * fac;

  // mobius_add(res, hb)
  float x2m = r0 * r0 + r1 * r1 + r2 * r2 + r3 * r3;
  float xy = r0 * hb0 + r1 * hb1 + r2 * hb2 + r3 * hb3;
#pragma unroll
  for (int o = 1; o < 16; o <<= 1) {
    x2m += __shfl_xor(x2m, o, 64);
    xy += __shfl_xor(xy, o, 64);
  }
  float k2 = 1.f + 2.f * c * xy;
  float ca = k2 + c * y2;
  float cb = 1.f - c * x2m;
  float inv = 1.f / fmaxf(k2 + c * c * x2m * y2, MIN_NORM);
  float a0 = (ca * r0 + cb * hb0) * inv;
  float a1 = (ca * r1 + cb * hb1) * inv;
  float a2 = (ca * r2 + cb * hb2) * inv;
  float a3 = (ca * r3 + cb * hb3) * inv;

  // logmap0
  float psq = a0 * a0 + a1 * a1 + a2 * a2 + a3 * a3;
#pragma unroll
  for (int o = 1; o < 16; o <<= 1) psq += __shfl_xor(psq, o, 64);
  float p_norm = fmaxf(sqrtf(psq), MIN_NORM);
  float art2 = artanh_clip(sc * p_norm);
  float fac2 = art2 / (sc * p_norm);

  ushort4 hv;
  hv.x = (unsigned short)f2bf(a0 * fac2);
  hv.y = (unsigned short)f2bf(a1 * fac2);
  hv.z = (unsigned short)f2bf(a2 * fac2);
  hv.w = (unsigned short)f2bf(a3 * fac2);
  *(ushort4*)&h[(size_t)r * 64 + q * 4] = hv;
}

// scan_a: per-block inclusive scan of cnt -> rowptr[1+gid]; blksum[b] = block total
__global__ __launch_bounds__(1024) void scan_a(const int* __restrict__ cnt,
                                               int* __restrict__ rowptr,
                                               int* __restrict__ blksum, int N) {
  __shared__ int wsums[16];
  int gid = blockIdx.x * 1024 + threadIdx.x;
  int lane = threadIdx.x & 63, w = threadIdx.x >> 6;
  int v = (gid < N) ? cnt[gid] : 0;
  int s = v;
#pragma unroll
  for (int d = 1; d < 64; d <<= 1) { int t = __shfl_up(s, d, 64); if (lane >= d) s += t; }
  if (lane == 63) wsums[w] = s;
  __syncthreads();
  if (w == 0 && lane < 16) {
    int ss = wsums[lane];
#pragma unroll
    for (int d = 1; d < 16; d <<= 1) { int u = __shfl_up(ss, d, 64); if (lane >= d) ss += u; }
    wsums[lane] = ss;
  }
  __syncthreads();
  if (w > 0) s += wsums[w - 1];
  if (gid < N) rowptr[1 + gid] = s;
  if (threadIdx.x == 1023) blksum[blockIdx.x] = s;
}

// scan_c: each block computes its own exclusive block offset from raw blksum, applies it
__global__ __launch_bounds__(1024) void scan_c(int* __restrict__ rowptr,
                                               const int* __restrict__ blksum,
                                               int N, int nblk) {
  __shared__ int s_off;
  if (threadIdx.x < 64) {
    int acc = 0;
    for (int bidx = threadIdx.x; bidx < (int)blockIdx.x; bidx += 64) acc += blksum[bidx];
#pragma unroll
    for (int off = 32; off; off >>= 1) acc += __shfl_xor(acc, off, 64);
    if (threadIdx.x == 0) s_off = acc;
  }
  __syncthreads();
  int gid = blockIdx.x * 1024 + threadIdx.x;
  if (gid == 0) rowptr[0] = 0;
  if (gid < N) rowptr[1 + gid] += s_off;
}

// scatter: rowptr doubles as cursor; packs (col, val) into int2
__global__ __launch_bounds__(256) void scatter_kernel(
    const int* __restrict__ row, const int* __restrict__ col,
    const float* __restrict__ vals, int* __restrict__ rowptr,
    int2* __restrict__ pairs, int E) {
  int i = blockIdx.x * blockDim.x + threadIdx.x;
  if (i < E) {
    int r = row[i];
    int pos = atomicAdd(&rowptr[r], 1);
    pairs[pos] = make_int2(col[i], __builtin_bit_cast(int, vals[i]));
  }
}

// segsum: wave per row, 4 subwaves x 16 lanes; each subwave one edge, each lane ushort4.
// Fused expmap0 + proj.
__global__ __launch_bounds__(256) void segsum_kernel(
    const unsigned short* __restrict__ h, const int* __restrict__ rowptr,
    const int2* __restrict__ pairs, const float* __restrict__ cptr,
    float* __restrict__ out, int N) {
  const int lane = threadIdx.x & 63;
  const int wid = threadIdx.x >> 6;
  const int sw = lane >> 4;   // subwave 0..3 (edge slot)
  const int q = lane & 15;    // dim quad
  int r = blockIdx.x * 4 + wid;
  if (r >= N) return;
  const float c = *cptr;
  const float sc = sqrtf(c);
  const float maxnorm = (1.0f - BALL_EPS) / sc;
  int st = (r > 0) ? rowptr[r - 1] : 0;
  int en = rowptr[r];
  st = __builtin_amdgcn_readfirstlane(st);
  en = __builtin_amdgcn_readfirstlane(en);

  float a0 = 0.f, a1 = 0.f, a2 = 0.f, a3 = 0.f;
#pragma unroll 2
  for (int i = st + sw; i < en; i += 4) {
    int2 pv = pairs[i];
    float vv = __builtin_bit_cast(float, pv.y);
    ushort4 hv = *(const ushort4*)&h[(size_t)pv.x * 64 + q * 4];
    a0 = fmaf(vv, bf2f(hv.x), a0);
    a1 = fmaf(vv, bf2f(hv.y), a1);
    a2 = fmaf(vv, bf2f(hv.z), a2);
    a3 = fmaf(vv, bf2f(hv.w), a3);
  }
  a0 += __shfl_xor(a0, 32, 64); a1 += __shfl_xor(a1, 32, 64);
  a2 += __shfl_xor(a2, 32, 64); a3 += __shfl_xor(a3, 32, 64);
  a0 += __shfl_xor(a0, 16, 64); a1 += __shfl_xor(a1, 16, 64);
  a2 += __shfl_xor(a2, 16, 64); a3 += __shfl_xor(a3, 16, 64);

  float sq = a0 * a0 + a1 * a1 + a2 * a2 + a3 * a3;
#pragma unroll
  for (int o = 1; o < 16; o <<= 1) sq += __shfl_xor(sq, o, 64);
  float un = fmaxf(sqrtf(sq), MIN_NORM);
  float th = tanhf(sc * un);
  float fac = th / (sc * un);
  float p0 = a0 * fac, p1 = a1 * fac, p2 = a2 * fac, p3 = a3 * fac;
  float psq = p0 * p0 + p1 * p1 + p2 * p2 + p3 * p3;
#pragma unroll
  for (int o = 1; o < 16; o <<= 1) psq += __shfl_xor(psq, o, 64);
  float pn = fmaxf(sqrtf(psq), MIN_NORM);
  if (pn > maxnorm) {
    float pf = maxnorm / pn;
    p0 *= pf; p1 *= pf; p2 *= pf; p3 *= pf;
  }
  if (sw == 0)
    *(float4*)&out[(size_t)r * 64 + q * 4] = make_float4(p0, p1, p2, p3);
}

// ---- fallback (atomic path, bf16 h) ----
__global__ __launch_bounds__(256) void edge_kernel(
    const unsigned short* __restrict__ h, const float* __restrict__ vals,
    const int* __restrict__ row, const int* __restrict__ col,
    float* __restrict__ out, int E) {
  const int lane = threadIdx.x & 63;
  const int wid0 = (blockIdx.x * blockDim.x + threadIdx.x) >> 6;
  const int nw = (gridDim.x * blockDim.x) >> 6;
  for (int e = wid0; e < E; e += nw) {
    int eu = __builtin_amdgcn_readfirstlane(e);
    float v = vals[eu];
    int r = row[eu];
    int cl = col[eu];
    atomicAdd(&out[(size_t)r * 64 + lane], v * bf2f(h[(size_t)cl * 64 + lane]));
  }
}

__global__ __launch_bounds__(256) void final_kernel(
    float* __restrict__ out, const float* __restrict__ cptr, int N) {
  const int lane = threadIdx.x & 63;
  const int wid0 = (blockIdx.x * blockDim.x + threadIdx.x) >> 6;
  const int nw = (gridDim.x * blockDim.x) >> 6;
  const float c = *cptr;
  const float sc = sqrtf(c);
  const float maxnorm = (1.0f - BALL_EPS) / sc;
  for (int r = wid0; r < N; r += nw) {
    float u = out[(size_t)r * 64 + lane];
    float un = fmaxf(sqrtf(wsum(u * u)), MIN_NORM);
    float th = tanhf(sc * un);
    float p = th * u / (sc * un);
    float pn = fmaxf(sqrtf(wsum(p * p)), MIN_NORM);
    if (pn > maxnorm) p = p / pn * maxnorm;
    out[(size_t)r * 64 + lane] = p;
  }
}

static inline size_t align256(size_t x) { return (x + 255) & ~(size_t)255; }

extern "C" void kernel_launch(void* const* d_in, const int* in_sizes, int n_in,
                              void* d_out, int out_size, void* d_ws, size_t ws_size,
                              hipStream_t stream) {
  const float* x = (const float*)d_in[0];      // [N,256]
  const float* W = (const float*)d_in[1];      // [256,64]
  const float* bias = (const float*)d_in[2];   // [64]
  const float* vals = (const float*)d_in[3];   // [E]
  const float* cptr = (const float*)d_in[4];   // scalar
  const int* row = (const int*)d_in[5];        // [E]
  const int* col = (const int*)d_in[6];        // [E]
  float* out = (float*)d_out;                  // [N,64]

  const int OUT = in_sizes[2];                 // 64
  const int IN = in_sizes[1] / OUT;            // 256
  const int N = in_sizes[0] / IN;              // 50000
  const int E = in_sizes[3];                   // 800000

  // ws layout: mx(f32, later aliased by pairs) | h(bf16) | x2 | rowptr | blksum | cnt
  char* ws = (char*)d_ws;
  size_t o_mx = 0;
  size_t o_h = align256(o_mx + (size_t)N * 64 * 4);
  size_t o_x2 = align256(o_h + (size_t)N * 64 * 2);
  size_t o_rowptr = align256(o_x2 + (size_t)N * 4);
  size_t o_blk = align256(o_rowptr + (size_t)(N + 1) * 4);
  size_t o_cnt = align256(o_blk + 1024 * 4);
  size_t needed = o_cnt + (size_t)N * 4;
  bool pairs_fit = (size_t)E * 8 <= o_h;       // pairs alias the dead mx region

  float* mx_ws = (float*)(ws + o_mx);
  unsigned short* h = (unsigned short*)(ws + o_h);
  float* x2_ws = (float*)(ws + o_x2);

  const int nb16 = (N + 15) / 16;
  const int G1 = (nb16 + 7) / 8;               // GEMM blocks (2 row-blocks per wave)
  const int HB = 256;                          // histogram blocks
  const int k1b_blocks = (N + 15) / 16;

  if (needed <= ws_size && pairs_fit) {
    int* rowptr = (int*)(ws + o_rowptr);
    int* blksum = (int*)(ws + o_blk);
    int* cnt = (int*)(ws + o_cnt);
    int2* pairs = (int2*)(ws + o_mx);          // alias: mx is dead after k1b

    const int nblk = (N + 1023) / 1024;
    const int eb = (E + 255) / 256;

    hipMemsetAsync(cnt, 0, (size_t)N * 4, stream);
    k1_gemm_hist<<<G1 + HB, 256, 0, stream>>>(x, W, mx_ws, x2_ws, N, row, cnt, E, G1);
    k1b_hyp<<<k1b_blocks, 256, 0, stream>>>(mx_ws, x2_ws, bias, cptr, h, N);
    scan_a<<<nblk, 1024, 0, stream>>>(cnt, rowptr, blksum, N);
    scan_c<<<nblk, 1024, 0, stream>>>(rowptr, blksum, N, nblk);
    scatter_kernel<<<eb, 256, 0, stream>>>(row, col, vals, rowptr, pairs, E);
    segsum_kernel<<<(N + 3) / 4, 256, 0, stream>>>(h, rowptr, pairs, cptr, out, N);
  } else {
    // fallback: atomic scatter path (needs only mx + h + x2)
    k1_gemm_hist<<<G1, 256, 0, stream>>>(x, W, mx_ws, x2_ws, N, row, (int*)nullptr, 0, G1);
    k1b_hyp<<<k1b_blocks, 256, 0, stream>>>(mx_ws, x2_ws, bias, cptr, h, N);
    hipMemsetAsync(d_out, 0, (size_t)out_size * sizeof(float), stream);
    edge_kernel<<<2048, 256, 0, stream>>>(h, vals, row, col, out, E);
    final_kernel<<<1024, 256, 0, stream>>>(out, cptr, N);
  }
}